// Round 6
// baseline (672.468 us; speedup 1.0000x reference)
//
#include <hip/hip_runtime.h>
#include <hip/hip_bf16.h>

#define BB 4
#define LL 2048
#define DD 512
#define HH 8
#define HD 64
#define UU 8
#define BH (BB*HH)
#define SCALE 0.125f
#define FILLX 48   // fill blocks per grid row; total fill blocks = FILLX*BH = 1536

typedef __attribute__((ext_vector_type(8))) short short8;
typedef __attribute__((ext_vector_type(4))) float f32x4;

__device__ __forceinline__ unsigned short bf16_rne(float x) {
    unsigned int u = __float_as_uint(x);
    unsigned int r = u + 0x7FFFu + ((u >> 16) & 1u);
    return (unsigned short)(r >> 16);
}

// ---------------- K1: per-(b,h) v sum + k column-sum; also zeroes map ------
__global__ __launch_bounds__(256) void kv_stats(const float* __restrict__ Kin,
                                                const float* __restrict__ Vin,
                                                float* __restrict__ vsum,
                                                float* __restrict__ ksum,
                                                int* __restrict__ map) {
    int bh = blockIdx.x; int b = bh / HH, h = bh % HH;
    int t = threadIdx.x; int d = t & 63; int g = t >> 6;
    map[bh*256 + t] = 0;                       // 32 blocks x 256 = 8192 = BB*LL
    const float* kb = Kin + (size_t)b*LL*DD + h*HD + d;
    const float* vb = Vin + (size_t)b*LL*DD + h*HD + d;
    float ak = 0.f, av = 0.f;
    for (int l = g; l < LL; l += 4) { ak += kb[(size_t)l*DD]; av += vb[(size_t)l*DD]; }
    __shared__ float sk[4][64], sv[4][64];
    sk[g][d] = ak; sv[g][d] = av;
    __syncthreads();
    if (g == 0) {
        ksum[bh*64 + d] = sk[0][d]+sk[1][d]+sk[2][d]+sk[3][d];
        vsum[bh*64 + d] = sv[0][d]+sv[1][d]+sv[2][d]+sv[3][d];
    }
}

// ---------------- K2: fused {M_measure via split-bf16 MFMA} + {Wfull zero-fill}
// grid (16+FILLX, BH), block 256. blockIdx.x<16 -> compute, else -> fill.
__global__ __launch_bounds__(256) void m_fused(const float* __restrict__ Q,
                                               const float* __restrict__ Kin,
                                               const float* __restrict__ ksum,
                                               float* __restrict__ M,
                                               f32x4* __restrict__ Wz) {
    if (blockIdx.x >= 16) {                    // ---- zero-fill path ----
        int fid = (blockIdx.x - 16) + FILLX * blockIdx.y;
        const f32x4 z = {0.f, 0.f, 0.f, 0.f};
        const size_t total = (size_t)BH*LL*LL/4;            // 33,554,432 f32x4
        const size_t stride = (size_t)FILLX*BH*256;
        for (size_t i = (size_t)fid*256 + threadIdx.x; i < total; i += stride)
            __builtin_nontemporal_store(z, &Wz[i]);
        return;
    }
    int qt = blockIdx.x;
    int bh = blockIdx.y; int b = bh / HH, h = bh % HH;
    const int t = threadIdx.x;
    const int lane = t & 63, w = t >> 6;
    const int c = lane & 15, G = lane >> 4;

    __shared__ unsigned short kHi[2][64*64];
    __shared__ unsigned short kLo[2][64*64];
    __shared__ float ksLds[64];
    __shared__ float sm[128];

    const float* qb = Q   + (size_t)b*LL*DD + h*HD;
    const float* kb = Kin + (size_t)b*LL*DD + h*HD;

    short8 a_hi[2][2], a_lo[2][2];
    #pragma unroll
    for (int g = 0; g < 2; g++) {
        int qrow = qt*128 + w*32 + g*16 + c;
        const float* qr = qb + (size_t)qrow*DD + G*8;
        #pragma unroll
        for (int dh = 0; dh < 2; dh++) {
            float4 x0 = *(const float4*)(qr + dh*32);
            float4 x1 = *(const float4*)(qr + dh*32 + 4);
            float x[8] = {x0.x,x0.y,x0.z,x0.w, x1.x,x1.y,x1.z,x1.w};
            short8 hi, lo;
            #pragma unroll
            for (int j = 0; j < 8; j++) {
                float xs = x[j] * SCALE;
                unsigned short hb = bf16_rne(xs);
                float hf = __uint_as_float((unsigned int)hb << 16);
                hi[j] = (short)hb;
                lo[j] = (short)bf16_rne(xs - hf);
            }
            a_hi[g][dh] = hi; a_lo[g][dh] = lo;
        }
    }
    if (t < 64) ksLds[t] = ksum[bh*64 + t];

    #pragma unroll
    for (int i = 0; i < 4; i++) {
        int f = t + i*256;
        int row = f >> 4, col4 = f & 15;
        float4 kv = *(const float4*)(kb + (size_t)row*DD + col4*4);
        float xs[4] = {kv.x, kv.y, kv.z, kv.w};
        unsigned short hb[4], lb[4];
        #pragma unroll
        for (int j = 0; j < 4; j++) {
            unsigned short hh = bf16_rne(xs[j]);
            float hf = __uint_as_float((unsigned int)hh << 16);
            hb[j] = hh; lb[j] = bf16_rne(xs[j] - hf);
        }
        int off = row*64 + (((col4>>1) ^ (row&7))<<3) + (col4&1)*4;
        uint2 uh; uh.x = hb[0] | ((unsigned)hb[1]<<16); uh.y = hb[2] | ((unsigned)hb[3]<<16);
        uint2 ul; ul.x = lb[0] | ((unsigned)lb[1]<<16); ul.y = lb[2] | ((unsigned)lb[3]<<16);
        *(uint2*)&kHi[0][off] = uh;
        *(uint2*)&kLo[0][off] = ul;
    }
    float se[2][4] = {};
    __syncthreads();

    for (int r = 0; r < 32; r++) {
        int p = r & 1;
        float4 stg[4];
        if (r < 31) {
            #pragma unroll
            for (int i = 0; i < 4; i++) {
                int f = t + i*256;
                int row = f >> 4, col4 = f & 15;
                stg[i] = *(const float4*)(kb + (size_t)((r+1)*64 + row)*DD + col4*4);
            }
        }
        #pragma unroll
        for (int kt = 0; kt < 4; kt++) {
            int rowIn = kt*16 + c;
            int sw = rowIn & 7;
            int base = rowIn*64;
            short8 bh0 = *(const short8*)&kHi[p][base + ((G       ^ sw)<<3)];
            short8 bh1 = *(const short8*)&kHi[p][base + (((G + 4) ^ sw)<<3)];
            short8 bl0 = *(const short8*)&kLo[p][base + ((G       ^ sw)<<3)];
            short8 bl1 = *(const short8*)&kLo[p][base + (((G + 4) ^ sw)<<3)];
            #pragma unroll
            for (int g = 0; g < 2; g++) {
                f32x4 acc = {0.f, 0.f, 0.f, 0.f};
                acc = __builtin_amdgcn_mfma_f32_16x16x32_bf16(a_hi[g][0], bh0, acc, 0, 0, 0);
                acc = __builtin_amdgcn_mfma_f32_16x16x32_bf16(a_hi[g][1], bh1, acc, 0, 0, 0);
                acc = __builtin_amdgcn_mfma_f32_16x16x32_bf16(a_lo[g][0], bh0, acc, 0, 0, 0);
                acc = __builtin_amdgcn_mfma_f32_16x16x32_bf16(a_lo[g][1], bh1, acc, 0, 0, 0);
                acc = __builtin_amdgcn_mfma_f32_16x16x32_bf16(a_hi[g][0], bl0, acc, 0, 0, 0);
                acc = __builtin_amdgcn_mfma_f32_16x16x32_bf16(a_hi[g][1], bl1, acc, 0, 0, 0);
                #pragma unroll
                for (int q4 = 0; q4 < 4; q4++) se[g][q4] += __expf(acc[q4]);
            }
        }
        if (r < 31) {
            #pragma unroll
            for (int i = 0; i < 4; i++) {
                int f = t + i*256;
                int row = f >> 4, col4 = f & 15;
                float xs[4] = {stg[i].x, stg[i].y, stg[i].z, stg[i].w};
                unsigned short hb[4], lb[4];
                #pragma unroll
                for (int j = 0; j < 4; j++) {
                    unsigned short hh = bf16_rne(xs[j]);
                    float hf = __uint_as_float((unsigned int)hh << 16);
                    hb[j] = hh; lb[j] = bf16_rne(xs[j] - hf);
                }
                int off = row*64 + (((col4>>1) ^ (row&7))<<3) + (col4&1)*4;
                uint2 uh; uh.x = hb[0] | ((unsigned)hb[1]<<16); uh.y = hb[2] | ((unsigned)hb[3]<<16);
                uint2 ul; ul.x = lb[0] | ((unsigned)lb[1]<<16); ul.y = lb[2] | ((unsigned)lb[3]<<16);
                *(uint2*)&kHi[p^1][off] = uh;
                *(uint2*)&kLo[p^1][off] = ul;
            }
        }
        __syncthreads();
    }

    #pragma unroll
    for (int g = 0; g < 2; g++)
        #pragma unroll
        for (int q4 = 0; q4 < 4; q4++) {
            float v = se[g][q4];
            v += __shfl_xor(v, 1);
            v += __shfl_xor(v, 2);
            v += __shfl_xor(v, 4);
            v += __shfl_xor(v, 8);
            se[g][q4] = v;
        }
    if (c == 0) {
        #pragma unroll
        for (int g = 0; g < 2; g++)
            #pragma unroll
            for (int q4 = 0; q4 < 4; q4++)
                sm[w*32 + g*16 + G*4 + q4] = se[g][q4];
    }
    __syncthreads();
    if (t < 128) {
        int qrow = qt*128 + t;
        const float* qr = qb + (size_t)qrow*DD;
        float dot = 0.f;
        for (int d0 = 0; d0 < 64; d0 += 4) {
            float4 qv = *(const float4*)(qr + d0);
            dot += qv.x*ksLds[d0] + qv.y*ksLds[d0+1] + qv.z*ksLds[d0+2] + qv.w*ksLds[d0+3];
        }
        M[bh*LL + qrow] = __logf(sm[t]) - __logf((float)LL) - dot * (SCALE/(float)LL);
    }
}

// ---------------- K3: top-8 per (b,h) + head-bit map scatter ----------------
__global__ __launch_bounds__(256) void top8(const float* __restrict__ M,
                                            int* __restrict__ idx,
                                            int* __restrict__ map) {
    int bh = blockIdx.x; int t = threadIdx.x;
    __shared__ float Ml[LL];
    __shared__ float vals[256];
    __shared__ int   vidx[256];
    for (int i = t; i < LL; i += 256) Ml[i] = M[bh*LL + i];
    __syncthreads();
    for (int r = 0; r < UU; r++) {
        float bv = -1e30f; int bi = 0;
        for (int i = t; i < LL; i += 256) {
            float v = Ml[i];
            if (v > bv) { bv = v; bi = i; }
        }
        vals[t] = bv; vidx[t] = bi;
        __syncthreads();
        for (int s = 128; s > 0; s >>= 1) {
            if (t < s) {
                if (vals[t+s] > vals[t] ||
                    (vals[t+s] == vals[t] && vidx[t+s] < vidx[t])) {
                    vals[t] = vals[t+s]; vidx[t] = vidx[t+s];
                }
            }
            __syncthreads();
        }
        if (t == 0) {
            int w = vidx[0];
            idx[bh*UU + r] = w;
            Ml[w] = -1e30f;
            atomicOr(&map[(bh/HH)*LL + w], 1 << (bh % HH));
        }
        __syncthreads();
    }
}

// ---------------- K4: full attention for the 256 active rows ----------------
__global__ __launch_bounds__(256) void active_attn(const float* __restrict__ Q,
                                                   const float* __restrict__ Kin,
                                                   const float* __restrict__ Vin,
                                                   const int* __restrict__ idx,
                                                   float* __restrict__ attn_o,
                                                   float* __restrict__ Wfull) {
    int e = blockIdx.x;
    int bh = e / UU;
    int b = bh / HH, h = bh % HH;
    int t = threadIdx.x;
    int l = idx[e];
    __shared__ float qs[64];
    __shared__ float w[LL];
    __shared__ float red[256];
    if (t < 64) qs[t] = Q[(size_t)b*LL*DD + (size_t)l*DD + h*HD + t];
    __syncthreads();
    const float* kb = Kin + (size_t)b*LL*DD + h*HD;
    float s[8];
    float mx = -1e30f;
    #pragma unroll
    for (int p = 0; p < 8; p++) {
        int m = t + p*256;
        const float* kr = kb + (size_t)m*DD;
        float acc = 0.f;
        for (int d0 = 0; d0 < 64; d0 += 4) {
            float4 kv = *(const float4*)(kr + d0);
            acc += qs[d0]*kv.x + qs[d0+1]*kv.y + qs[d0+2]*kv.z + qs[d0+3]*kv.w;
        }
        s[p] = acc * SCALE;
        mx = fmaxf(mx, s[p]);
    }
    red[t] = mx; __syncthreads();
    for (int st = 128; st > 0; st >>= 1) { if (t < st) red[t] = fmaxf(red[t], red[t+st]); __syncthreads(); }
    mx = red[0]; __syncthreads();
    float lsum = 0.f;
    #pragma unroll
    for (int p = 0; p < 8; p++) { s[p] = __expf(s[p] - mx); lsum += s[p]; }
    red[t] = lsum; __syncthreads();
    for (int st = 128; st > 0; st >>= 1) { if (t < st) red[t] += red[t+st]; __syncthreads(); }
    float inv = 1.0f / red[0]; __syncthreads();
    float* wrow = Wfull + ((size_t)bh*LL + l) * LL;
    #pragma unroll
    for (int p = 0; p < 8; p++) {
        int m = t + p*256;
        float wn = s[p] * inv;
        w[m] = wn;
        wrow[m] = wn;
    }
    __syncthreads();
    const float* vb = Vin + (size_t)b*LL*DD + h*HD;
    int d = t & 63, g = t >> 6;
    float acc = 0.f;
    for (int m = g*512; m < (g+1)*512; m++) acc += w[m] * vb[(size_t)m*DD + d];
    __syncthreads();
    red[t] = acc; __syncthreads();
    if (g == 0) attn_o[e*64 + d] = red[d] + red[64+d] + red[128+d] + red[192+d];
}

// ---------------- K5: default output row per batch ----------------
__global__ __launch_bounds__(256) void def_out_kernel(const float* __restrict__ vsum,
                                                      const float* __restrict__ w_out,
                                                      const float* __restrict__ b_out,
                                                      float* __restrict__ defo) {
    int b = blockIdx.x; int t = threadIdx.x;
    __shared__ float x[DD];
    for (int i = t; i < DD; i += 256) x[i] = vsum[(b*HH + (i >> 6))*64 + (i & 63)] * (1.0f/LL);
    __syncthreads();
    for (int dp = t; dp < DD; dp += 256) {
        const float* wr = w_out + (size_t)dp*DD;
        float acc = b_out[dp];
        for (int d0 = 0; d0 < DD; d0 += 4) {
            float4 wv = *(const float4*)(wr + d0);
            acc += x[d0]*wv.x + x[d0+1]*wv.y + x[d0+2]*wv.z + x[d0+3]*wv.w;
        }
        defo[b*DD + dp] = acc;
    }
}

// ---------------- K6: assemble out = attn_output @ w_out^T + b_out ----------
__global__ __launch_bounds__(256) void out_kernel(const float* __restrict__ defo,
                                                  const float* __restrict__ vsum,
                                                  const float* __restrict__ attn_o,
                                                  const int* __restrict__ idx,
                                                  const int* __restrict__ map,
                                                  const float* __restrict__ w_out,
                                                  const float* __restrict__ b_out,
                                                  float* __restrict__ out) {
    int l = blockIdx.x, b = blockIdx.y;
    int t = threadIdx.x;
    float* orow = out + ((size_t)b*LL + l) * DD;
    int mp = map[b*LL + l];
    if (mp == 0) {
        const float* dr = defo + b*DD;
        orow[t] = dr[t]; orow[t + 256] = dr[t + 256];
        return;
    }
    __shared__ float x[DD];
    for (int i = t; i < DD; i += 256) x[i] = vsum[(b*HH + (i >> 6))*64 + (i & 63)] * (1.0f/LL);
    __syncthreads();
    if (t < 64) {
        for (int h = 0; h < HH; h++) if (mp & (1 << h)) {
            int bh = b*HH + h;
            int e = bh*UU;
            for (int j = 0; j < UU; j++) if (idx[bh*UU + j] == l) { e = bh*UU + j; break; }
            x[h*64 + t] = attn_o[e*64 + t];
        }
    }
    __syncthreads();
    for (int dp = t; dp < DD; dp += 256) {
        const float* wr = w_out + (size_t)dp*DD;
        float acc = b_out[dp];
        for (int d0 = 0; d0 < DD; d0 += 4) {
            float4 wv = *(const float4*)(wr + d0);
            acc += x[d0]*wv.x + x[d0+1]*wv.y + x[d0+2]*wv.z + x[d0+3]*wv.w;
        }
        orow[dp] = acc;
    }
}

extern "C" void kernel_launch(void* const* d_in, const int* in_sizes, int n_in,
                              void* d_out, int out_size, void* d_ws, size_t ws_size,
                              hipStream_t stream) {
    const float* Q     = (const float*)d_in[0];
    const float* Kin   = (const float*)d_in[1];
    const float* Vin   = (const float*)d_in[2];
    const float* w_out = (const float*)d_in[3];
    const float* b_out = (const float*)d_in[4];

    float* out   = (float*)d_out;
    float* Wfull = out + (size_t)BB*LL*DD;

    char* ws = (char*)d_ws;
    float* vsum   = (float*)(ws);                        // [32][64]
    float* ksum   = (float*)(ws + 8192);                 // [32][64]
    float* M      = (float*)(ws + 16384);                // [32][2048]
    int*   idx    = (int*)  (ws + 16384 + 262144);       // [32][8]
    float* attn_o = (float*)(ws + 16384 + 262144 + 1024);          // [256][64]
    int*   map    = (int*)  (ws + 16384 + 262144 + 1024 + 65536);  // [4][2048]
    float* defo   = (float*)(ws + 16384 + 262144 + 1024 + 65536 + 32768); // [4][512]

    kv_stats<<<BH, 256, 0, stream>>>(Kin, Vin, vsum, ksum, map);
    m_fused<<<dim3(16 + FILLX, BH), 256, 0, stream>>>(Q, Kin, ksum, M, (f32x4*)Wfull);
    top8<<<BH, 256, 0, stream>>>(M, idx, map);
    active_attn<<<BH*UU, 256, 0, stream>>>(Q, Kin, Vin, idx, attn_o, Wfull);
    def_out_kernel<<<BB, 256, 0, stream>>>(vsum, w_out, b_out, defo);
    out_kernel<<<dim3(LL, BB), 256, 0, stream>>>(defo, vsum, attn_o, idx, map, w_out, b_out, out);
}

// Round 7
// 567.724 us; speedup vs baseline: 1.1845x; 1.1845x over previous
//
#include <hip/hip_runtime.h>
#include <hip/hip_bf16.h>

#define BB 4
#define LL 2048
#define DD 512
#define HH 8
#define HD 64
#define UU 8
#define BH (BB*HH)
#define SCALE 0.125f

typedef __attribute__((ext_vector_type(8))) short short8;
typedef __attribute__((ext_vector_type(4))) float f32x4;

__device__ __forceinline__ unsigned short bf16_rne(float x) {
    unsigned int u = __float_as_uint(x);
    unsigned int r = u + 0x7FFFu + ((u >> 16) & 1u);
    return (unsigned short)(r >> 16);
}

// ---------------- K0: zero-fill Wfull (536 MB) + small scratch -------------
__global__ __launch_bounds__(256) void fill_w(f32x4* __restrict__ Wz,
                                              float* __restrict__ vsum,
                                              float* __restrict__ ksum,
                                              int* __restrict__ map) {
    const f32x4 z = {0.f, 0.f, 0.f, 0.f};
    const size_t total = (size_t)BH*LL*LL/4;            // 33,554,432 f32x4
    const size_t stride = (size_t)gridDim.x*256;
    for (size_t i = (size_t)blockIdx.x*256 + threadIdx.x; i < total; i += stride)
        __builtin_nontemporal_store(z, &Wz[i]);
    if (blockIdx.x == 0) {
        int t = threadIdx.x;
        #pragma unroll
        for (int j = 0; j < 8; j++) { vsum[t + j*256] = 0.f; ksum[t + j*256] = 0.f; }
        #pragma unroll
        for (int j = 0; j < 32; j++) map[t + j*256] = 0;
    }
}

// ---------------- K1: per-(b,h) v sum and k column-sum (256 blocks) --------
__global__ __launch_bounds__(256) void kv_stats(const float* __restrict__ Kin,
                                                const float* __restrict__ Vin,
                                                float* __restrict__ vsum,
                                                float* __restrict__ ksum) {
    int bh = blockIdx.x; int b = bh / HH, h = bh % HH;
    int chunk = blockIdx.y;
    int t = threadIdx.x; int d = t & 63; int g = t >> 6;
    const float* kb = Kin + (size_t)b*LL*DD + h*HD + d;
    const float* vb = Vin + (size_t)b*LL*DD + h*HD + d;
    float ak = 0.f, av = 0.f;
    for (int l = chunk*256 + g; l < chunk*256 + 256; l += 4) {
        ak += kb[(size_t)l*DD]; av += vb[(size_t)l*DD];
    }
    __shared__ float sk[4][64], sv[4][64];
    sk[g][d] = ak; sv[g][d] = av;
    __syncthreads();
    if (g == 0) {
        atomicAdd(&ksum[bh*64 + d], sk[0][d]+sk[1][d]+sk[2][d]+sk[3][d]);
        atomicAdd(&vsum[bh*64 + d], sv[0][d]+sv[1][d]+sv[2][d]+sv[3][d]);
    }
}

// ---------------- K2: M_measure via split-bf16 MFMA ------------------------
// grid (16, BH), block 256 = 4 waves; each block: 128 qrows x all 2048 krows.
__global__ __launch_bounds__(256) void m_mfma(const float* __restrict__ Q,
                                              const float* __restrict__ Kin,
                                              const float* __restrict__ ksum,
                                              float* __restrict__ M) {
    int qt = blockIdx.x;
    int bh = blockIdx.y; int b = bh / HH, h = bh % HH;
    const int t = threadIdx.x;
    const int lane = t & 63, w = t >> 6;
    const int c = lane & 15, G = lane >> 4;

    __shared__ unsigned short kHi[2][64*64];
    __shared__ unsigned short kLo[2][64*64];
    __shared__ float ksLds[64];
    __shared__ float sm[128];

    const float* qb = Q   + (size_t)b*LL*DD + h*HD;
    const float* kb = Kin + (size_t)b*LL*DD + h*HD;

    short8 a_hi[2][2], a_lo[2][2];
    #pragma unroll
    for (int g = 0; g < 2; g++) {
        int qrow = qt*128 + w*32 + g*16 + c;
        const float* qr = qb + (size_t)qrow*DD + G*8;
        #pragma unroll
        for (int dh = 0; dh < 2; dh++) {
            float4 x0 = *(const float4*)(qr + dh*32);
            float4 x1 = *(const float4*)(qr + dh*32 + 4);
            float x[8] = {x0.x,x0.y,x0.z,x0.w, x1.x,x1.y,x1.z,x1.w};
            short8 hi, lo;
            #pragma unroll
            for (int j = 0; j < 8; j++) {
                float xs = x[j] * SCALE;
                unsigned short hb = bf16_rne(xs);
                float hf = __uint_as_float((unsigned int)hb << 16);
                hi[j] = (short)hb;
                lo[j] = (short)bf16_rne(xs - hf);
            }
            a_hi[g][dh] = hi; a_lo[g][dh] = lo;
        }
    }
    if (t < 64) ksLds[t] = ksum[bh*64 + t];

    #pragma unroll
    for (int i = 0; i < 4; i++) {
        int f = t + i*256;
        int row = f >> 4, col4 = f & 15;
        float4 kv = *(const float4*)(kb + (size_t)row*DD + col4*4);
        float xs[4] = {kv.x, kv.y, kv.z, kv.w};
        unsigned short hb[4], lb[4];
        #pragma unroll
        for (int j = 0; j < 4; j++) {
            unsigned short hh = bf16_rne(xs[j]);
            float hf = __uint_as_float((unsigned int)hh << 16);
            hb[j] = hh; lb[j] = bf16_rne(xs[j] - hf);
        }
        int off = row*64 + (((col4>>1) ^ (row&7))<<3) + (col4&1)*4;
        uint2 uh; uh.x = hb[0] | ((unsigned)hb[1]<<16); uh.y = hb[2] | ((unsigned)hb[3]<<16);
        uint2 ul; ul.x = lb[0] | ((unsigned)lb[1]<<16); ul.y = lb[2] | ((unsigned)lb[3]<<16);
        *(uint2*)&kHi[0][off] = uh;
        *(uint2*)&kLo[0][off] = ul;
    }
    float se[2][4] = {};
    __syncthreads();

    for (int r = 0; r < 32; r++) {
        int p = r & 1;
        float4 stg[4];
        if (r < 31) {
            #pragma unroll
            for (int i = 0; i < 4; i++) {
                int f = t + i*256;
                int row = f >> 4, col4 = f & 15;
                stg[i] = *(const float4*)(kb + (size_t)((r+1)*64 + row)*DD + col4*4);
            }
        }
        #pragma unroll
        for (int kt = 0; kt < 4; kt++) {
            int rowIn = kt*16 + c;
            int sw = rowIn & 7;
            int base = rowIn*64;
            short8 bh0 = *(const short8*)&kHi[p][base + ((G       ^ sw)<<3)];
            short8 bh1 = *(const short8*)&kHi[p][base + (((G + 4) ^ sw)<<3)];
            short8 bl0 = *(const short8*)&kLo[p][base + ((G       ^ sw)<<3)];
            short8 bl1 = *(const short8*)&kLo[p][base + (((G + 4) ^ sw)<<3)];
            #pragma unroll
            for (int g = 0; g < 2; g++) {
                f32x4 acc = {0.f, 0.f, 0.f, 0.f};
                acc = __builtin_amdgcn_mfma_f32_16x16x32_bf16(a_hi[g][0], bh0, acc, 0, 0, 0);
                acc = __builtin_amdgcn_mfma_f32_16x16x32_bf16(a_hi[g][1], bh1, acc, 0, 0, 0);
                acc = __builtin_amdgcn_mfma_f32_16x16x32_bf16(a_lo[g][0], bh0, acc, 0, 0, 0);
                acc = __builtin_amdgcn_mfma_f32_16x16x32_bf16(a_lo[g][1], bh1, acc, 0, 0, 0);
                acc = __builtin_amdgcn_mfma_f32_16x16x32_bf16(a_hi[g][0], bl0, acc, 0, 0, 0);
                acc = __builtin_amdgcn_mfma_f32_16x16x32_bf16(a_hi[g][1], bl1, acc, 0, 0, 0);
                #pragma unroll
                for (int q4 = 0; q4 < 4; q4++) se[g][q4] += __expf(acc[q4]);
            }
        }
        if (r < 31) {
            #pragma unroll
            for (int i = 0; i < 4; i++) {
                int f = t + i*256;
                int row = f >> 4, col4 = f & 15;
                float xs[4] = {stg[i].x, stg[i].y, stg[i].z, stg[i].w};
                unsigned short hb[4], lb[4];
                #pragma unroll
                for (int j = 0; j < 4; j++) {
                    unsigned short hh = bf16_rne(xs[j]);
                    float hf = __uint_as_float((unsigned int)hh << 16);
                    hb[j] = hh; lb[j] = bf16_rne(xs[j] - hf);
                }
                int off = row*64 + (((col4>>1) ^ (row&7))<<3) + (col4&1)*4;
                uint2 uh; uh.x = hb[0] | ((unsigned)hb[1]<<16); uh.y = hb[2] | ((unsigned)hb[3]<<16);
                uint2 ul; ul.x = lb[0] | ((unsigned)lb[1]<<16); ul.y = lb[2] | ((unsigned)lb[3]<<16);
                *(uint2*)&kHi[p^1][off] = uh;
                *(uint2*)&kLo[p^1][off] = ul;
            }
        }
        __syncthreads();
    }

    #pragma unroll
    for (int g = 0; g < 2; g++)
        #pragma unroll
        for (int q4 = 0; q4 < 4; q4++) {
            float v = se[g][q4];
            v += __shfl_xor(v, 1);
            v += __shfl_xor(v, 2);
            v += __shfl_xor(v, 4);
            v += __shfl_xor(v, 8);
            se[g][q4] = v;
        }
    if (c == 0) {
        #pragma unroll
        for (int g = 0; g < 2; g++)
            #pragma unroll
            for (int q4 = 0; q4 < 4; q4++)
                sm[w*32 + g*16 + G*4 + q4] = se[g][q4];
    }
    __syncthreads();
    if (t < 128) {
        int qrow = qt*128 + t;
        const float* qr = qb + (size_t)qrow*DD;
        float dot = 0.f;
        for (int d0 = 0; d0 < 64; d0 += 4) {
            float4 qv = *(const float4*)(qr + d0);
            dot += qv.x*ksLds[d0] + qv.y*ksLds[d0+1] + qv.z*ksLds[d0+2] + qv.w*ksLds[d0+3];
        }
        M[bh*LL + qrow] = __logf(sm[t]) - __logf((float)LL) - dot * (SCALE/(float)LL);
    }
}

// ---------------- K3: top-8 per (b,h) + head-bit map scatter ----------------
__global__ __launch_bounds__(256) void top8(const float* __restrict__ M,
                                            int* __restrict__ idx,
                                            int* __restrict__ map) {
    int bh = blockIdx.x; int t = threadIdx.x;
    __shared__ float Ml[LL];
    __shared__ float vals[256];
    __shared__ int   vidx[256];
    for (int i = t; i < LL; i += 256) Ml[i] = M[bh*LL + i];
    __syncthreads();
    for (int r = 0; r < UU; r++) {
        float bv = -1e30f; int bi = 0;
        for (int i = t; i < LL; i += 256) {
            float v = Ml[i];
            if (v > bv) { bv = v; bi = i; }
        }
        vals[t] = bv; vidx[t] = bi;
        __syncthreads();
        for (int s = 128; s > 0; s >>= 1) {
            if (t < s) {
                if (vals[t+s] > vals[t] ||
                    (vals[t+s] == vals[t] && vidx[t+s] < vidx[t])) {
                    vals[t] = vals[t+s]; vidx[t] = vidx[t+s];
                }
            }
            __syncthreads();
        }
        if (t == 0) {
            int w = vidx[0];
            idx[bh*UU + r] = w;
            Ml[w] = -1e30f;
            atomicOr(&map[(bh/HH)*LL + w], 1 << (bh % HH));
        }
        __syncthreads();
    }
}

// ---------------- K4: full attention for the 256 active rows ----------------
__global__ __launch_bounds__(256) void active_attn(const float* __restrict__ Q,
                                                   const float* __restrict__ Kin,
                                                   const float* __restrict__ Vin,
                                                   const int* __restrict__ idx,
                                                   float* __restrict__ attn_o,
                                                   float* __restrict__ Wfull) {
    int e = blockIdx.x;
    int bh = e / UU;
    int b = bh / HH, h = bh % HH;
    int t = threadIdx.x;
    int l = idx[e];
    __shared__ float qs[64];
    __shared__ float w[LL];
    __shared__ float red[256];
    if (t < 64) qs[t] = Q[(size_t)b*LL*DD + (size_t)l*DD + h*HD + t];
    __syncthreads();
    const float* kb = Kin + (size_t)b*LL*DD + h*HD;
    float s[8];
    float mx = -1e30f;
    #pragma unroll
    for (int p = 0; p < 8; p++) {
        int m = t + p*256;
        const float* kr = kb + (size_t)m*DD;
        float acc = 0.f;
        for (int d0 = 0; d0 < 64; d0 += 4) {
            float4 kv = *(const float4*)(kr + d0);
            acc += qs[d0]*kv.x + qs[d0+1]*kv.y + qs[d0+2]*kv.z + qs[d0+3]*kv.w;
        }
        s[p] = acc * SCALE;
        mx = fmaxf(mx, s[p]);
    }
    red[t] = mx; __syncthreads();
    for (int st = 128; st > 0; st >>= 1) { if (t < st) red[t] = fmaxf(red[t], red[t+st]); __syncthreads(); }
    mx = red[0]; __syncthreads();
    float lsum = 0.f;
    #pragma unroll
    for (int p = 0; p < 8; p++) { s[p] = __expf(s[p] - mx); lsum += s[p]; }
    red[t] = lsum; __syncthreads();
    for (int st = 128; st > 0; st >>= 1) { if (t < st) red[t] += red[t+st]; __syncthreads(); }
    float inv = 1.0f / red[0]; __syncthreads();
    float* wrow = Wfull + ((size_t)bh*LL + l) * LL;
    #pragma unroll
    for (int p = 0; p < 8; p++) {
        int m = t + p*256;
        float wn = s[p] * inv;
        w[m] = wn;
        wrow[m] = wn;
    }
    __syncthreads();
    const float* vb = Vin + (size_t)b*LL*DD + h*HD;
    int d = t & 63, g = t >> 6;
    float acc = 0.f;
    for (int m = g*512; m < (g+1)*512; m++) acc += w[m] * vb[(size_t)m*DD + d];
    __syncthreads();
    red[t] = acc; __syncthreads();
    if (g == 0) attn_o[e*64 + d] = red[d] + red[64+d] + red[128+d] + red[192+d];
}

// ---------------- K5: default output row per batch ----------------
__global__ __launch_bounds__(256) void def_out_kernel(const float* __restrict__ vsum,
                                                      const float* __restrict__ w_out,
                                                      const float* __restrict__ b_out,
                                                      float* __restrict__ defo) {
    int b = blockIdx.x; int t = threadIdx.x;
    __shared__ float x[DD];
    for (int i = t; i < DD; i += 256) x[i] = vsum[(b*HH + (i >> 6))*64 + (i & 63)] * (1.0f/LL);
    __syncthreads();
    for (int dp = t; dp < DD; dp += 256) {
        const float* wr = w_out + (size_t)dp*DD;
        float acc = b_out[dp];
        for (int d0 = 0; d0 < DD; d0 += 4) {
            float4 wv = *(const float4*)(wr + d0);
            acc += x[d0]*wv.x + x[d0+1]*wv.y + x[d0+2]*wv.z + x[d0+3]*wv.w;
        }
        defo[b*DD + dp] = acc;
    }
}

// ---------------- K6: assemble out = attn_output @ w_out^T + b_out ----------
__global__ __launch_bounds__(256) void out_kernel(const float* __restrict__ defo,
                                                  const float* __restrict__ vsum,
                                                  const float* __restrict__ attn_o,
                                                  const int* __restrict__ idx,
                                                  const int* __restrict__ map,
                                                  const float* __restrict__ w_out,
                                                  const float* __restrict__ b_out,
                                                  float* __restrict__ out) {
    int l = blockIdx.x, b = blockIdx.y;
    int t = threadIdx.x;
    float* orow = out + ((size_t)b*LL + l) * DD;
    int mp = map[b*LL + l];
    if (mp == 0) {
        const float* dr = defo + b*DD;
        orow[t] = dr[t]; orow[t + 256] = dr[t + 256];
        return;
    }
    __shared__ float x[DD];
    for (int i = t; i < DD; i += 256) x[i] = vsum[(b*HH + (i >> 6))*64 + (i & 63)] * (1.0f/LL);
    __syncthreads();
    if (t < 64) {
        for (int h = 0; h < HH; h++) if (mp & (1 << h)) {
            int bh = b*HH + h;
            int e = bh*UU;
            for (int j = 0; j < UU; j++) if (idx[bh*UU + j] == l) { e = bh*UU + j; break; }
            x[h*64 + t] = attn_o[e*64 + t];
        }
    }
    __syncthreads();
    for (int dp = t; dp < DD; dp += 256) {
        const float* wr = w_out + (size_t)dp*DD;
        float acc = b_out[dp];
        for (int d0 = 0; d0 < DD; d0 += 4) {
            float4 wv = *(const float4*)(wr + d0);
            acc += x[d0]*wv.x + x[d0+1]*wv.y + x[d0+2]*wv.z + x[d0+3]*wv.w;
        }
        orow[dp] = acc;
    }
}

extern "C" void kernel_launch(void* const* d_in, const int* in_sizes, int n_in,
                              void* d_out, int out_size, void* d_ws, size_t ws_size,
                              hipStream_t stream) {
    const float* Q     = (const float*)d_in[0];
    const float* Kin   = (const float*)d_in[1];
    const float* Vin   = (const float*)d_in[2];
    const float* w_out = (const float*)d_in[3];
    const float* b_out = (const float*)d_in[4];

    float* out   = (float*)d_out;
    float* Wfull = out + (size_t)BB*LL*DD;

    char* ws = (char*)d_ws;
    float* vsum   = (float*)(ws);                        // [32][64]
    float* ksum   = (float*)(ws + 8192);                 // [32][64]
    float* M      = (float*)(ws + 16384);                // [32][2048]
    int*   idx    = (int*)  (ws + 16384 + 262144);       // [32][8]
    float* attn_o = (float*)(ws + 16384 + 262144 + 1024);          // [256][64]
    int*   map    = (int*)  (ws + 16384 + 262144 + 1024 + 65536);  // [4][2048]
    float* defo   = (float*)(ws + 16384 + 262144 + 1024 + 65536 + 32768); // [4][512]

    fill_w<<<2048, 256, 0, stream>>>((f32x4*)Wfull, vsum, ksum, map);
    kv_stats<<<dim3(BH, 8), 256, 0, stream>>>(Kin, Vin, vsum, ksum);
    m_mfma<<<dim3(16, BH), 256, 0, stream>>>(Q, Kin, ksum, M);
    top8<<<BH, 256, 0, stream>>>(M, idx, map);
    active_attn<<<BH*UU, 256, 0, stream>>>(Q, Kin, Vin, idx, attn_o, Wfull);
    def_out_kernel<<<BB, 256, 0, stream>>>(vsum, w_out, b_out, defo);
    out_kernel<<<dim3(LL, BB), 256, 0, stream>>>(defo, vsum, attn_o, idx, map, w_out, b_out, out);
}

// Round 8
// 504.665 us; speedup vs baseline: 1.3325x; 1.1250x over previous
//
#include <hip/hip_runtime.h>
#include <hip/hip_bf16.h>

#define BB 4
#define LL 2048
#define DD 512
#define HH 8
#define HD 64
#define UU 8
#define BH (BB*HH)
#define SCALE 0.125f

typedef __attribute__((ext_vector_type(8))) short short8;
typedef __attribute__((ext_vector_type(4))) float f32x4;
typedef unsigned short ushortT;

__device__ __forceinline__ unsigned short bf16_rne(float x) {
    unsigned int u = __float_as_uint(x);
    unsigned int r = u + 0x7FFFu + ((u >> 16) & 1u);
    return (unsigned short)(r >> 16);
}

// ---------------- K1: per-(b,h) v sum and k column-sum (256 blocks) --------
__global__ __launch_bounds__(256) void kv_stats(const float* __restrict__ Kin,
                                                const float* __restrict__ Vin,
                                                float* __restrict__ vsum,
                                                float* __restrict__ ksum) {
    int bh = blockIdx.x; int b = bh / HH, h = bh % HH;
    int chunk = blockIdx.y;
    int t = threadIdx.x; int d = t & 63; int g = t >> 6;
    const float* kb = Kin + (size_t)b*LL*DD + h*HD + d;
    const float* vb = Vin + (size_t)b*LL*DD + h*HD + d;
    float ak = 0.f, av = 0.f;
    for (int l = chunk*256 + g; l < chunk*256 + 256; l += 4) {
        ak += kb[(size_t)l*DD]; av += vb[(size_t)l*DD];
    }
    __shared__ float sk[4][64], sv[4][64];
    sk[g][d] = ak; sv[g][d] = av;
    __syncthreads();
    if (g == 0) {
        atomicAdd(&ksum[bh*64 + d], sk[0][d]+sk[1][d]+sk[2][d]+sk[3][d]);
        atomicAdd(&vsum[bh*64 + d], sv[0][d]+sv[1][d]+sv[2][d]+sv[3][d]);
    }
}

// ---------------- K1b: one-time K -> split-bf16 swizzled tile images -------
// 1024 blocks = 32 bh x 32 tiles; tile image = 4096 ushorts (64 rows x 64),
// swizzle baked in so m_mfma can stage with a LINEAR copy.
__global__ __launch_bounds__(256) void khi_prep(const float* __restrict__ Kin,
                                                ushortT* __restrict__ KhiG,
                                                ushortT* __restrict__ KloG) {
    int blk = blockIdx.x;
    int bh = blk >> 5, tile = blk & 31;
    int b = bh / HH, h = bh % HH;
    int t = threadIdx.x;
    const float* kb = Kin + (size_t)b*LL*DD + h*HD;
    #pragma unroll
    for (int i = 0; i < 4; i++) {
        int f = t + i*256;
        int row = f >> 4, col4 = f & 15;
        float4 kv = *(const float4*)(kb + (size_t)(tile*64 + row)*DD + col4*4);
        float xs[4] = {kv.x, kv.y, kv.z, kv.w};
        unsigned short hb[4], lb[4];
        #pragma unroll
        for (int j = 0; j < 4; j++) {
            unsigned short hh = bf16_rne(xs[j]);
            float hf = __uint_as_float((unsigned int)hh << 16);
            hb[j] = hh; lb[j] = bf16_rne(xs[j] - hf);
        }
        int off = row*64 + (((col4>>1) ^ (row&7))<<3) + (col4&1)*4;
        uint2 uh; uh.x = hb[0] | ((unsigned)hb[1]<<16); uh.y = hb[2] | ((unsigned)hb[3]<<16);
        uint2 ul; ul.x = lb[0] | ((unsigned)lb[1]<<16); ul.y = lb[2] | ((unsigned)lb[3]<<16);
        *(uint2*)&KhiG[(size_t)blk*4096 + off] = uh;
        *(uint2*)&KloG[(size_t)blk*4096 + off] = ul;
    }
}

// ---------------- K2: M_measure via split-bf16 MFMA (linear-copy staging) --
__global__ __launch_bounds__(256) void m_mfma(const float* __restrict__ Q,
                                              const ushortT* __restrict__ KhiG,
                                              const ushortT* __restrict__ KloG,
                                              const float* __restrict__ ksum,
                                              float* __restrict__ M) {
    int qt = blockIdx.x;
    int bh = blockIdx.y; int b = bh / HH, h = bh % HH;
    const int t = threadIdx.x;
    const int lane = t & 63, w = t >> 6;
    const int c = lane & 15, G = lane >> 4;

    __shared__ unsigned short kHi[2][4096];
    __shared__ unsigned short kLo[2][4096];
    __shared__ float ksLds[64];
    __shared__ float sm[128];

    const float* qb = Q + (size_t)b*LL*DD + h*HD;
    const ushortT* khg = KhiG + (size_t)bh*32*4096;
    const ushortT* klg = KloG + (size_t)bh*32*4096;

    // A fragments (Q), scale folded, hi/lo split, in regs
    short8 a_hi[2][2], a_lo[2][2];
    #pragma unroll
    for (int g = 0; g < 2; g++) {
        int qrow = qt*128 + w*32 + g*16 + c;
        const float* qr = qb + (size_t)qrow*DD + G*8;
        #pragma unroll
        for (int dh = 0; dh < 2; dh++) {
            float4 x0 = *(const float4*)(qr + dh*32);
            float4 x1 = *(const float4*)(qr + dh*32 + 4);
            float x[8] = {x0.x,x0.y,x0.z,x0.w, x1.x,x1.y,x1.z,x1.w};
            short8 hi, lo;
            #pragma unroll
            for (int j = 0; j < 8; j++) {
                float xs = x[j] * SCALE;
                unsigned short hb = bf16_rne(xs);
                float hf = __uint_as_float((unsigned int)hb << 16);
                hi[j] = (short)hb;
                lo[j] = (short)bf16_rne(xs - hf);
            }
            a_hi[g][dh] = hi; a_lo[g][dh] = lo;
        }
    }
    if (t < 64) ksLds[t] = ksum[bh*64 + t];

    // prologue: linear copy of tile 0 images
    #pragma unroll
    for (int i = 0; i < 2; i++) {
        *(uint4*)&kHi[0][i*2048 + t*8] = *(const uint4*)&khg[i*2048 + t*8];
        *(uint4*)&kLo[0][i*2048 + t*8] = *(const uint4*)&klg[i*2048 + t*8];
    }
    float se[2][4] = {};
    __syncthreads();

    for (int r = 0; r < 32; r++) {
        int p = r & 1;
        uint4 sh[2], sl[2];
        if (r < 31) {                      // issue next-tile loads early
            #pragma unroll
            for (int i = 0; i < 2; i++) {
                sh[i] = *(const uint4*)&khg[(size_t)(r+1)*4096 + i*2048 + t*8];
                sl[i] = *(const uint4*)&klg[(size_t)(r+1)*4096 + i*2048 + t*8];
            }
        }
        #pragma unroll
        for (int kt = 0; kt < 4; kt++) {
            int rowIn = kt*16 + c;
            int sw = rowIn & 7;
            int base = rowIn*64;
            short8 bh0 = *(const short8*)&kHi[p][base + ((G       ^ sw)<<3)];
            short8 bh1 = *(const short8*)&kHi[p][base + (((G + 4) ^ sw)<<3)];
            short8 bl0 = *(const short8*)&kLo[p][base + ((G       ^ sw)<<3)];
            short8 bl1 = *(const short8*)&kLo[p][base + (((G + 4) ^ sw)<<3)];
            #pragma unroll
            for (int g = 0; g < 2; g++) {
                f32x4 acc = {0.f, 0.f, 0.f, 0.f};
                acc = __builtin_amdgcn_mfma_f32_16x16x32_bf16(a_hi[g][0], bh0, acc, 0, 0, 0);
                acc = __builtin_amdgcn_mfma_f32_16x16x32_bf16(a_hi[g][1], bh1, acc, 0, 0, 0);
                acc = __builtin_amdgcn_mfma_f32_16x16x32_bf16(a_lo[g][0], bh0, acc, 0, 0, 0);
                acc = __builtin_amdgcn_mfma_f32_16x16x32_bf16(a_lo[g][1], bh1, acc, 0, 0, 0);
                acc = __builtin_amdgcn_mfma_f32_16x16x32_bf16(a_hi[g][0], bl0, acc, 0, 0, 0);
                acc = __builtin_amdgcn_mfma_f32_16x16x32_bf16(a_hi[g][1], bl1, acc, 0, 0, 0);
                #pragma unroll
                for (int q4 = 0; q4 < 4; q4++) se[g][q4] += __expf(acc[q4]);
            }
        }
        if (r < 31) {                      // linear conflict-free ds_write
            #pragma unroll
            for (int i = 0; i < 2; i++) {
                *(uint4*)&kHi[p^1][i*2048 + t*8] = sh[i];
                *(uint4*)&kLo[p^1][i*2048 + t*8] = sl[i];
            }
        }
        __syncthreads();
    }

    #pragma unroll
    for (int g = 0; g < 2; g++)
        #pragma unroll
        for (int q4 = 0; q4 < 4; q4++) {
            float v = se[g][q4];
            v += __shfl_xor(v, 1);
            v += __shfl_xor(v, 2);
            v += __shfl_xor(v, 4);
            v += __shfl_xor(v, 8);
            se[g][q4] = v;
        }
    if (c == 0) {
        #pragma unroll
        for (int g = 0; g < 2; g++)
            #pragma unroll
            for (int q4 = 0; q4 < 4; q4++)
                sm[w*32 + g*16 + G*4 + q4] = se[g][q4];
    }
    __syncthreads();
    if (t < 128) {
        int qrow = qt*128 + t;
        const float* qr = qb + (size_t)qrow*DD;
        float dot = 0.f;
        for (int d0 = 0; d0 < 64; d0 += 4) {
            float4 qv = *(const float4*)(qr + d0);
            dot += qv.x*ksLds[d0] + qv.y*ksLds[d0+1] + qv.z*ksLds[d0+2] + qv.w*ksLds[d0+3];
        }
        M[bh*LL + qrow] = __logf(sm[t]) - __logf((float)LL) - dot * (SCALE/(float)LL);
    }
}

// ---------------- K3: top-8 per (b,h) + head-bit map scatter ----------------
__global__ __launch_bounds__(256) void top8(const float* __restrict__ M,
                                            int* __restrict__ idx,
                                            int* __restrict__ map) {
    int bh = blockIdx.x; int t = threadIdx.x;
    __shared__ float Ml[LL];
    __shared__ float vals[256];
    __shared__ int   vidx[256];
    for (int i = t; i < LL; i += 256) Ml[i] = M[bh*LL + i];
    __syncthreads();
    for (int r = 0; r < UU; r++) {
        float bv = -1e30f; int bi = 0;
        for (int i = t; i < LL; i += 256) {
            float v = Ml[i];
            if (v > bv) { bv = v; bi = i; }
        }
        vals[t] = bv; vidx[t] = bi;
        __syncthreads();
        for (int s = 128; s > 0; s >>= 1) {
            if (t < s) {
                if (vals[t+s] > vals[t] ||
                    (vals[t+s] == vals[t] && vidx[t+s] < vidx[t])) {
                    vals[t] = vals[t+s]; vidx[t] = vidx[t+s];
                }
            }
            __syncthreads();
        }
        if (t == 0) {
            int w = vidx[0];
            idx[bh*UU + r] = w;
            Ml[w] = -1e30f;
            atomicOr(&map[(bh/HH)*LL + w], 1 << (bh % HH));
        }
        __syncthreads();
    }
}

// ---------------- K4: active-row attention (+4 fused default-output blocks) -
__global__ __launch_bounds__(256) void active_attn(const float* __restrict__ Q,
                                                   const float* __restrict__ Kin,
                                                   const float* __restrict__ Vin,
                                                   const int* __restrict__ idx,
                                                   const float* __restrict__ vsum,
                                                   const float* __restrict__ w_out,
                                                   const float* __restrict__ b_out,
                                                   float* __restrict__ attn_o,
                                                   float* __restrict__ defo,
                                                   float* __restrict__ Wfull) {
    __shared__ float qs[64];
    __shared__ float w[LL];
    __shared__ float red[256];
    int t = threadIdx.x;
    if (blockIdx.x >= BH*UU) {             // ---- default-output path ----
        int b = blockIdx.x - BH*UU;
        for (int i = t; i < DD; i += 256) w[i] = vsum[(b*HH + (i >> 6))*64 + (i & 63)] * (1.0f/LL);
        __syncthreads();
        for (int dp = t; dp < DD; dp += 256) {
            const float* wr = w_out + (size_t)dp*DD;
            float acc = b_out[dp];
            for (int d0 = 0; d0 < DD; d0 += 4) {
                float4 wv = *(const float4*)(wr + d0);
                acc += w[d0]*wv.x + w[d0+1]*wv.y + w[d0+2]*wv.z + w[d0+3]*wv.w;
            }
            defo[b*DD + dp] = acc;
        }
        return;
    }
    int e = blockIdx.x;
    int bh = e / UU;
    int b = bh / HH, h = bh % HH;
    int l = idx[e];
    if (t < 64) qs[t] = Q[(size_t)b*LL*DD + (size_t)l*DD + h*HD + t];
    __syncthreads();
    const float* kb = Kin + (size_t)b*LL*DD + h*HD;
    float s[8];
    float mx = -1e30f;
    #pragma unroll
    for (int p = 0; p < 8; p++) {
        int m = t + p*256;
        const float* kr = kb + (size_t)m*DD;
        float acc = 0.f;
        for (int d0 = 0; d0 < 64; d0 += 4) {
            float4 kv = *(const float4*)(kr + d0);
            acc += qs[d0]*kv.x + qs[d0+1]*kv.y + qs[d0+2]*kv.z + qs[d0+3]*kv.w;
        }
        s[p] = acc * SCALE;
        mx = fmaxf(mx, s[p]);
    }
    red[t] = mx; __syncthreads();
    for (int st = 128; st > 0; st >>= 1) { if (t < st) red[t] = fmaxf(red[t], red[t+st]); __syncthreads(); }
    mx = red[0]; __syncthreads();
    float lsum = 0.f;
    #pragma unroll
    for (int p = 0; p < 8; p++) { s[p] = __expf(s[p] - mx); lsum += s[p]; }
    red[t] = lsum; __syncthreads();
    for (int st = 128; st > 0; st >>= 1) { if (t < st) red[t] += red[t+st]; __syncthreads(); }
    float inv = 1.0f / red[0]; __syncthreads();
    float* wrow = Wfull + ((size_t)bh*LL + l) * LL;
    #pragma unroll
    for (int p = 0; p < 8; p++) {
        int m = t + p*256;
        float wn = s[p] * inv;
        w[m] = wn;
        wrow[m] = wn;
    }
    __syncthreads();
    const float* vb = Vin + (size_t)b*LL*DD + h*HD;
    int d = t & 63, g = t >> 6;
    float acc = 0.f;
    for (int m = g*512; m < (g+1)*512; m++) acc += w[m] * vb[(size_t)m*DD + d];
    __syncthreads();
    red[t] = acc; __syncthreads();
    if (g == 0) attn_o[e*64 + d] = red[d] + red[64+d] + red[128+d] + red[192+d];
}

// ---------------- K6: assemble out = attn_output @ w_out^T + b_out ----------
__global__ __launch_bounds__(256) void out_kernel(const float* __restrict__ defo,
                                                  const float* __restrict__ vsum,
                                                  const float* __restrict__ attn_o,
                                                  const int* __restrict__ idx,
                                                  const int* __restrict__ map,
                                                  const float* __restrict__ w_out,
                                                  const float* __restrict__ b_out,
                                                  float* __restrict__ out) {
    int l = blockIdx.x, b = blockIdx.y;
    int t = threadIdx.x;
    float* orow = out + ((size_t)b*LL + l) * DD;
    int mp = map[b*LL + l];
    if (mp == 0) {
        const float* dr = defo + b*DD;
        orow[t] = dr[t]; orow[t + 256] = dr[t + 256];
        return;
    }
    __shared__ float x[DD];
    for (int i = t; i < DD; i += 256) x[i] = vsum[(b*HH + (i >> 6))*64 + (i & 63)] * (1.0f/LL);
    __syncthreads();
    if (t < 64) {
        for (int h = 0; h < HH; h++) if (mp & (1 << h)) {
            int bh = b*HH + h;
            int e = bh*UU;
            for (int j = 0; j < UU; j++) if (idx[bh*UU + j] == l) { e = bh*UU + j; break; }
            x[h*64 + t] = attn_o[e*64 + t];
        }
    }
    __syncthreads();
    for (int dp = t; dp < DD; dp += 256) {
        const float* wr = w_out + (size_t)dp*DD;
        float acc = b_out[dp];
        for (int d0 = 0; d0 < DD; d0 += 4) {
            float4 wv = *(const float4*)(wr + d0);
            acc += x[d0]*wv.x + x[d0+1]*wv.y + x[d0+2]*wv.z + x[d0+3]*wv.w;
        }
        orow[dp] = acc;
    }
}

extern "C" void kernel_launch(void* const* d_in, const int* in_sizes, int n_in,
                              void* d_out, int out_size, void* d_ws, size_t ws_size,
                              hipStream_t stream) {
    const float* Q     = (const float*)d_in[0];
    const float* Kin   = (const float*)d_in[1];
    const float* Vin   = (const float*)d_in[2];
    const float* w_out = (const float*)d_in[3];
    const float* b_out = (const float*)d_in[4];

    float* out   = (float*)d_out;
    float* Wfull = out + (size_t)BB*LL*DD;

    char* ws = (char*)d_ws;
    float*   vsum   = (float*)(ws);                        // [32][64]
    float*   ksum   = (float*)(ws + 8192);                 // [32][64]
    float*   M      = (float*)(ws + 16384);                // [32][2048]
    int*     idx    = (int*)  (ws + 16384 + 262144);       // [32][8]
    float*   attn_o = (float*)(ws + 16384 + 262144 + 1024);          // [256][64]
    int*     map    = (int*)  (ws + 16384 + 262144 + 1024 + 65536);  // [4][2048]
    float*   defo   = (float*)(ws + 16384 + 262144 + 1024 + 65536 + 32768); // [4][512]
    ushortT* KhiG   = (ushortT*)(ws + (1u<<20));           // 8 MB tile images
    ushortT* KloG   = (ushortT*)(ws + (10u<<20));          // 8 MB

    hipMemsetAsync(Wfull, 0, (size_t)BH*LL*LL*sizeof(float), stream);
    hipMemsetAsync(map, 0, (size_t)BB*LL*sizeof(int), stream);
    hipMemsetAsync(ws, 0, 16384, stream);   // vsum + ksum

    kv_stats<<<dim3(BH, 8), 256, 0, stream>>>(Kin, Vin, vsum, ksum);
    khi_prep<<<1024, 256, 0, stream>>>(Kin, KhiG, KloG);
    m_mfma<<<dim3(16, BH), 256, 0, stream>>>(Q, KhiG, KloG, ksum, M);
    top8<<<BH, 256, 0, stream>>>(M, idx, map);
    active_attn<<<BH*UU + BB, 256, 0, stream>>>(Q, Kin, Vin, idx, vsum, w_out, b_out,
                                                attn_o, defo, Wfull);
    out_kernel<<<dim3(LL, BB), 256, 0, stream>>>(defo, vsum, attn_o, idx, map, w_out, b_out, out);
}